// Round 14
// baseline (1597.970 us; speedup 1.0000x reference)
//
#include <hip/hip_runtime.h>

#define NN 100000
#define NE 600000
#define HH 128
#define NL 5
#define BN_EPS 1e-5f
#define NB 391    // (NN+255)/256
#define NGB 25000 // gather blocks = NN*64/256 (exact)
#define L2B 32    // level-2 reduce blocks
#define RPB2 782  // ceil(NGB/L2B) partial rows per level-2 block

typedef float f4 __attribute__((ext_vector_type(4)));
typedef float f2 __attribute__((ext_vector_type(2)));
typedef _Float16 h8 __attribute__((ext_vector_type(8)));
typedef _Float16 h2x __attribute__((ext_vector_type(2)));

// ---------------- edge-index dtype probe + normalize to int32 ----------------
__global__ void k_probe(const unsigned long long* __restrict__ e, int* __restrict__ flag) {
    if (blockIdx.x == 0 && threadIdx.x == 0) {
        int ok = 1;
        for (int i = 0; i < 64; ++i)
            if (e[i] >= (unsigned long long)NN) ok = 0;
        *flag = ok; // 1 => int64, 0 => int32
    }
}

__global__ void k_convert(const void* __restrict__ src, const int* __restrict__ flag,
                          int* __restrict__ dst) {
    int i = blockIdx.x * 256 + threadIdx.x;
    if (i >= 2 * NE) return;
    if (*flag) dst[i] = (int)((const long long*)src)[i];
    else       dst[i] = ((const int*)src)[i];
}

__global__ void k_zero(int* __restrict__ p, int n) {
    int i = blockIdx.x * 256 + threadIdx.x;
    if (i < n) p[i] = 0;
}

// ---------------- degree / dinv ----------------
__global__ void k_count_deg(const int* __restrict__ col, int* __restrict__ degi) {
    int e = blockIdx.x * 256 + threadIdx.x;
    if (e < NE) atomicAdd(&degi[col[e]], 1);
}

__global__ void k_dinv(const int* __restrict__ degi, float* __restrict__ dinv) {
    int i = blockIdx.x * 256 + threadIdx.x;
    if (i < NN) dinv[i] = rsqrtf((float)degi[i] + 1.0f);
}

// ---------------- prefix scan ----------------
__global__ __launch_bounds__(256) void k_scan1(const int* __restrict__ degi,
                                               int* __restrict__ incl,
                                               int* __restrict__ blocksums) {
    __shared__ int sd[256];
    int tid = threadIdx.x;
    int i = blockIdx.x * 256 + tid;
    int v = (i < NN) ? degi[i] : 0;
    sd[tid] = v;
    __syncthreads();
#pragma unroll
    for (int off = 1; off < 256; off <<= 1) {
        int t = (tid >= off) ? sd[tid - off] : 0;
        __syncthreads();
        sd[tid] += t;
        __syncthreads();
    }
    if (i < NN) incl[i] = sd[tid];
    if (tid == 255) blocksums[blockIdx.x] = sd[255];
}

__global__ __launch_bounds__(512) void k_scan2(const int* __restrict__ blocksums,
                                               int* __restrict__ blockoffs) {
    __shared__ int sd[512];
    int tid = threadIdx.x;
    int v = (tid < NB) ? blocksums[tid] : 0;
    sd[tid] = v;
    __syncthreads();
#pragma unroll
    for (int off = 1; off < 512; off <<= 1) {
        int t = (tid >= off) ? sd[tid - off] : 0;
        __syncthreads();
        sd[tid] += t;
        __syncthreads();
    }
    if (tid < NB) blockoffs[tid] = sd[tid] - v;
}

__global__ void k_scan3(const int* __restrict__ incl, const int* __restrict__ degi,
                        const int* __restrict__ blockoffs,
                        int* __restrict__ offsets, int* __restrict__ cursor) {
    int i = blockIdx.x * 256 + threadIdx.x;
    if (i >= NN) return;
    offsets[i] = incl[i] - degi[i] + blockoffs[blockIdx.x];
    cursor[i] = 0;
}

__global__ void k_scatter(const int* __restrict__ ei, const float* __restrict__ dinv,
                          const int* __restrict__ offsets, int* __restrict__ cursor,
                          int2* __restrict__ csr) {
    int e = blockIdx.x * 256 + threadIdx.x;
    if (e >= NE) return;
    int r = ei[e], c = ei[NE + e];
    int pos = offsets[c] + atomicAdd(&cursor[c], 1);
    int2 v;
    v.x = r;
    v.y = __float_as_int(dinv[r] * dinv[c]);
    csr[pos] = v;
}

// ---- transpose + split-cast weights: Wt{hi,lo}[l][n][k] from W[l][k][n] (fp32) ----
__global__ void k_wt(const float* __restrict__ W, _Float16* __restrict__ Wt_hi,
                     _Float16* __restrict__ Wt_lo) {
    int gid = blockIdx.x * 256 + threadIdx.x; // over NL*128*128
    if (gid >= NL * HH * HH) return;
    int l = gid >> 14;
    int rem = gid & 16383;
    int n = rem >> 7;
    int k = rem & 127;
    float w = W[l * HH * HH + k * HH + n];
    _Float16 hi = (_Float16)w;
    _Float16 lo = (_Float16)(w - (float)hi);
    Wt_hi[gid] = hi;
    Wt_lo[gid] = lo;
}

// ---- BN scale/shift from level2 partials (merged sred2+prep) ----
// mode=0 -> identity; else sum the L2B level2 rows, compute sc/sh.
__global__ void k_prep(const float* __restrict__ level2, const float* __restrict__ gamma,
                       const float* __restrict__ beta, int mode, float* __restrict__ scsh) {
    int k = threadIdx.x; // 128 threads
    float sc = 1.0f, sh = 0.0f;
    if (mode) {
        float s = 0.0f, q = 0.0f;
#pragma unroll
        for (int b = 0; b < L2B; ++b) {
            s += level2[(size_t)b * 256 + k];
            q += level2[(size_t)b * 256 + 128 + k];
        }
        const float inv_n = 1.0f / (float)NN;
        float mean = s * inv_n;
        float var  = q * inv_n - mean * mean;
        sc = gamma[k] * rsqrtf(var + BN_EPS);
        sh = beta[k] - mean * sc;
    }
    scsh[k] = sc;
    scsh[128 + k] = sh;
}

// ---------------- fused GEMM: h1 = relu?(bn(A)) @ W, split-fp16 MFMA, fp32 I/O ------
// 256-row tile/block (391 blocks, single dispatch round at 2 blocks/CU w/ 64KB LDS).
// Swapped-operand MFMA: D = W^T·X^T = C^T => f4 C-stores.
// h1 = Xhi@Whi + Xhi@Wlo + Xlo@Whi  (error ~2^-22 rel; effectively fp32)
__global__ __launch_bounds__(256) void k_gemm(const float* __restrict__ A,
                                              const _Float16* __restrict__ Wt_hi,
                                              const _Float16* __restrict__ Wt_lo,
                                              const float* __restrict__ scsh,
                                              float negmul,
                                              float* __restrict__ C) {
    __shared__ _Float16 sBH[16384];  // 32 KB
    __shared__ _Float16 sBL[16384];  // 32 KB
    const int tid = threadIdx.x;

#pragma unroll
    for (int it = 0; it < 8; ++it) {
        int g  = it * 256 + tid;
        int rr = g & 15;
        int kg = (g >> 4) & 3;
        int kc = (g >> 6) & 3;
        int n  = g >> 8;
        int glob = (n * 16 + rr) * HH + kc * 32 + kg * 8;
        *reinterpret_cast<h8*>(&sBH[g * 8]) = *reinterpret_cast<const h8*>(Wt_hi + glob);
        *reinterpret_cast<h8*>(&sBL[g * 8]) = *reinterpret_cast<const h8*>(Wt_lo + glob);
    }
    __syncthreads();

    const int wave = tid >> 6;
    const int lane = tid & 63;
    const int r    = lane & 15;
    const int kg   = lane >> 4;        // 0..3
    const int row0 = blockIdx.x * 256 + wave * 64;

    f4 acc[4][8];
#pragma unroll
    for (int m = 0; m < 4; ++m)
#pragma unroll
        for (int n = 0; n < 8; ++n) acc[m][n] = (f4)0.0f;

    const float* Ap[4];
#pragma unroll
    for (int m = 0; m < 4; ++m) {
        int ra = row0 + m * 16 + r;
        if (ra >= NN) ra = NN - 1;
        Ap[m] = A + (size_t)ra * HH + kg * 8;
    }

#pragma unroll
    for (int kc = 0; kc < 4; ++kc) {
        const int k0 = kc * 32 + kg * 8;
        f4 scA = *reinterpret_cast<const f4*>(scsh + k0);
        f4 scB = *reinterpret_cast<const f4*>(scsh + k0 + 4);
        f4 shA = *reinterpret_cast<const f4*>(scsh + 128 + k0);
        f4 shB = *reinterpret_cast<const f4*>(scsh + 128 + k0 + 4);
        h8 ahi[4], alo[4];
#pragma unroll
        for (int m = 0; m < 4; ++m) {
            f4 ax = *reinterpret_cast<const f4*>(Ap[m] + kc * 32);
            f4 ay = *reinterpret_cast<const f4*>(Ap[m] + kc * 32 + 4);
#pragma unroll
            for (int j = 0; j < 4; ++j) {
                float t;
                t = fmaf(ax[j], scA[j], shA[j]); t = fmaxf(t, t * negmul);
                ahi[m][j] = (_Float16)t;      alo[m][j] = (_Float16)(t - (float)ahi[m][j]);
                t = fmaf(ay[j], scB[j], shB[j]); t = fmaxf(t, t * negmul);
                ahi[m][j + 4] = (_Float16)t;  alo[m][j + 4] = (_Float16)(t - (float)ahi[m][j + 4]);
            }
        }
#pragma unroll
        for (int n = 0; n < 8; ++n) {
            int g = n * 256 + kc * 64 + lane;
            h8 bh = *reinterpret_cast<const h8*>(&sBH[g * 8]);
            h8 bl = *reinterpret_cast<const h8*>(&sBL[g * 8]);
#pragma unroll
            for (int m = 0; m < 4; ++m) {
                acc[m][n] = __builtin_amdgcn_mfma_f32_16x16x32_f16(bh, ahi[m], acc[m][n], 0, 0, 0);
                acc[m][n] = __builtin_amdgcn_mfma_f32_16x16x32_f16(bl, ahi[m], acc[m][n], 0, 0, 0);
                acc[m][n] = __builtin_amdgcn_mfma_f32_16x16x32_f16(bh, alo[m], acc[m][n], 0, 0, 0);
            }
        }
    }

    // D^T mapping: lane (r,kg) holds C[row0 + m*16 + r][n*16 + kg*4 + i], i=0..3 -> f4
#pragma unroll
    for (int m = 0; m < 4; ++m) {
        int rr = row0 + m * 16 + r;
        if (rr < NN) {
            float* Crow = C + (size_t)rr * HH + kg * 4;
#pragma unroll
            for (int n = 0; n < 8; ++n)
                *reinterpret_cast<f4*>(Crow + n * 16) = acc[m][n];
        }
    }
}

// ------- gather aggregation (fp32) + fused BN partial stats -------
// One wave per node (proven round-11 config: VGPR-lean, 100K-wave TLP, 4-deep
// masked unroll). Epilogue: 4-wave LDS reduce of sum/sumsq -> one coalesced
// 1KB partial row per block (NO atomics, no extra h2 read pass).
__global__ __launch_bounds__(256) void k_gather(const float* __restrict__ h1,
                                                const int* __restrict__ offsets,
                                                const int* __restrict__ degi,
                                                const int2* __restrict__ csr,
                                                const float* __restrict__ dinv,
                                                float* __restrict__ h2,
                                                float* __restrict__ partial) {
    __shared__ f2 ls[4][64];
    __shared__ f2 lss[4][64];
    int gid  = blockIdx.x * 256 + threadIdx.x;
    int node = gid >> 6;        // grid exact: node < NN always
    int lane = gid & 63;
    int wid  = threadIdx.x >> 6;
    float di = dinv[node];
    f2 acc0 = reinterpret_cast<const f2*>(h1 + (size_t)node * HH)[lane] * (di * di);
    f2 acc1 = (f2)0.0f, acc2 = (f2)0.0f, acc3 = (f2)0.0f;
    const int start = offsets[node];
    const int end   = start + degi[node];
    for (int b = start; b < end; b += 4) {
        int2 ce0 = csr[b];
        int2 ce1 = (b + 1 < end) ? csr[b + 1] : make_int2(0, 0);
        int2 ce2 = (b + 2 < end) ? csr[b + 2] : make_int2(0, 0);
        int2 ce3 = (b + 3 < end) ? csr[b + 3] : make_int2(0, 0);
        f2 v0 = reinterpret_cast<const f2*>(h1 + (size_t)ce0.x * HH)[lane];
        f2 v1 = reinterpret_cast<const f2*>(h1 + (size_t)ce1.x * HH)[lane];
        f2 v2 = reinterpret_cast<const f2*>(h1 + (size_t)ce2.x * HH)[lane];
        f2 v3 = reinterpret_cast<const f2*>(h1 + (size_t)ce3.x * HH)[lane];
        acc0 += v0 * __int_as_float(ce0.y);
        acc1 += v1 * __int_as_float(ce1.y);
        acc2 += v2 * __int_as_float(ce2.y);
        acc3 += v3 * __int_as_float(ce3.y);
    }
    acc0 += acc2;
    acc1 += acc3;
    acc0 += acc1;
    reinterpret_cast<f2*>(h2 + (size_t)node * HH)[lane] = acc0;

    // fused BN partial stats
    ls[wid][lane] = acc0;
    lss[wid][lane] = acc0 * acc0;
    __syncthreads();
    if (threadIdx.x < 64) {
        int c = threadIdx.x;
        f2 s = ls[0][c] + ls[1][c] + ls[2][c] + ls[3][c];
        f2 q = lss[0][c] + lss[1][c] + lss[2][c] + lss[3][c];
        f2* pp = reinterpret_cast<f2*>(partial + (size_t)blockIdx.x * 256);
        pp[c] = s;        // cols [0..127]: sum
        pp[64 + c] = q;   // cols [128..255]: sumsq
    }
}

// ------- stats level-2: 32 blocks each sum ~782 partial rows (coalesced) -------
__global__ void k_sred1(const float* __restrict__ partial, float* __restrict__ level2) {
    int c = threadIdx.x; // 256
    int b0 = blockIdx.x * RPB2;
    int b1 = b0 + RPB2;
    if (b1 > NGB) b1 = NGB;
    float s = 0.0f;
    for (int b = b0; b < b1; ++b) s += partial[(size_t)b * 256 + c];
    level2[(size_t)blockIdx.x * 256 + c] = s;
}

// ------- final-layer BN apply + ReLU: fp32 h2 -> fp16 x5 (scsh input) -------
__global__ void k_bnapply(const float* __restrict__ h2, const float* __restrict__ scsh,
                          _Float16* __restrict__ xh) {
    int idx = blockIdx.x * 256 + threadIdx.x; // over NN*64 pairs
    if (idx >= NN * 64) return;
    int cp = idx & 63;
    float sc0 = scsh[2 * cp],       sc1 = scsh[2 * cp + 1];
    float sh0 = scsh[128 + 2 * cp], sh1 = scsh[128 + 2 * cp + 1];
    f2 v = reinterpret_cast<const f2*>(h2)[idx];
    float t0 = fmaf(v[0], sc0, sh0);
    float t1 = fmaf(v[1], sc1, sh1);
    t0 = fmaxf(t0, 0.0f);
    t1 = fmaxf(t1, 0.0f);
    h2x o;
    o[0] = (_Float16)t0;
    o[1] = (_Float16)t1;
    reinterpret_cast<h2x*>(xh)[idx] = o;
}

// ---------------- final: 16 lanes per edge, fp16 rows, fp32 math ----------------
__global__ __launch_bounds__(256) void k_final(const _Float16* __restrict__ x,
                                               const int* __restrict__ ei,
                                               const float* __restrict__ fcw,
                                               const float* __restrict__ fcb,
                                               float* __restrict__ out) {
    int gid  = blockIdx.x * 256 + threadIdx.x;
    int e    = gid >> 4;          // 16 lanes per edge
    int l16  = gid & 15;
    if (e >= NE) return;
    int a = ei[e];
    int b = ei[NE + e];
    h8 va = *reinterpret_cast<const h8*>(x + (size_t)a * HH + l16 * 8);
    h8 vb = *reinterpret_cast<const h8*>(x + (size_t)b * HH + l16 * 8);
    f4 w0 = *reinterpret_cast<const f4*>(fcw + l16 * 8);
    f4 w1 = *reinterpret_cast<const f4*>(fcw + l16 * 8 + 4);
    float p = 0.0f;
#pragma unroll
    for (int j = 0; j < 4; ++j) {
        p += (float)va[j] * (float)vb[j] * w0[j];
        p += (float)va[j + 4] * (float)vb[j + 4] * w1[j];
    }
#pragma unroll
    for (int off = 8; off > 0; off >>= 1) p += __shfl_xor(p, off, 64);
    if (l16 == 0) out[e] = 1.0f / (1.0f + expf(-(p + fcb[0])));
}

extern "C" void kernel_launch(void* const* d_in, const int* in_sizes, int n_in,
                              void* d_out, int out_size, void* d_ws, size_t ws_size,
                              hipStream_t stream) {
    const float* x   = (const float*)d_in[0];
    const void*  ei_raw = d_in[1];
    const float* cw  = (const float*)d_in[2];
    // d_in[3] = conv_b: cancels exactly through BatchNorm -> unused
    const float* gam = (const float*)d_in[4];
    const float* bet = (const float*)d_in[5];
    const float* fcw = (const float*)d_in[6];
    const float* fcb = (const float*)d_in[7];
    float* out = (float*)d_out;

    const size_t NH = (size_t)NN * HH;
    unsigned char* p = (unsigned char*)d_ws;
    float* h1 = (float*)p;       p += NH * 4;            // fp32 gemm out
    float* h2 = (float*)p;       p += NH * 4;            // fp32 aggregated
    _Float16* xh = (_Float16*)p; p += NH * 2;            // fp16 x5 for edge head
    _Float16* WtH = (_Float16*)p; p += (size_t)NL * HH * HH * 2;
    _Float16* WtL = (_Float16*)p; p += (size_t)NL * HH * HH * 2;
    int2*  csr   = (int2*)p;     p += (size_t)NE * 8;
    float* dinv  = (float*)p;    p += NN * 4;
    float* scsh  = (float*)p;    p += (NL + 1) * 256 * 4;
    float* partial = (float*)p;  p += (size_t)NGB * 256 * 4;  // 25.6 MB
    float* level2  = (float*)p;  p += (size_t)L2B * 256 * 4;
    int*   ei    = (int*)p;      p += (size_t)2 * NE * 4;
    int*   degi  = (int*)p;      p += NN * 4;
    int*   incl  = (int*)p;      p += NN * 4;
    int*   offsets = (int*)p;    p += NN * 4;
    int*   cursor  = (int*)p;    p += NN * 4;
    int*   blocksums = (int*)p;  p += NB * 4;
    int*   blockoffs = (int*)p;  p += NB * 4;
    int*   flag  = (int*)p;

    // normalize edge index dtype to int32
    k_probe<<<1, 64, 0, stream>>>((const unsigned long long*)ei_raw, flag);
    k_convert<<<(2 * NE + 255) / 256, 256, 0, stream>>>(ei_raw, flag, ei);

    // degrees -> dinv; CSR build
    k_zero<<<(NN + 255) / 256, 256, 0, stream>>>(degi, NN);
    k_count_deg<<<(NE + 255) / 256, 256, 0, stream>>>(ei + NE, degi);
    k_dinv<<<(NN + 255) / 256, 256, 0, stream>>>(degi, dinv);
    k_scan1<<<NB, 256, 0, stream>>>(degi, incl, blocksums);
    k_scan2<<<1, 512, 0, stream>>>(blocksums, blockoffs);
    k_scan3<<<NB, 256, 0, stream>>>(incl, degi, blockoffs, offsets, cursor);
    k_scatter<<<(NE + 255) / 256, 256, 0, stream>>>(ei, dinv, offsets, cursor, csr);

    // split weights (fp16 hi/lo, transposed)
    k_wt<<<(NL * HH * HH + 255) / 256, 256, 0, stream>>>(cw, WtH, WtL);

    for (int l = 0; l < NL; ++l) {
        // scsh for this layer from previous layer's level2 partials (identity for l=0)
        k_prep<<<1, 128, 0, stream>>>(
            level2,
            (l == 0) ? gam : gam + (size_t)(l - 1) * HH,
            (l == 0) ? bet : bet + (size_t)(l - 1) * HH,
            (l == 0) ? 0 : 1, scsh + (size_t)l * 256);
        k_gemm<<<(NN + 255) / 256, 256, 0, stream>>>(
            (l == 0) ? x : h2, WtH + (size_t)l * HH * HH, WtL + (size_t)l * HH * HH,
            scsh + (size_t)l * 256, (l == 0) ? 1.0f : 0.0f, h1);
        k_gather<<<NGB, 256, 0, stream>>>(h1, offsets, degi, csr, dinv, h2, partial);
        k_sred1<<<L2B, 256, 0, stream>>>(partial, level2);
    }
    // layer-5 scsh, then materialize x5 (fp16) for the edge head
    k_prep<<<1, 128, 0, stream>>>(level2, gam + (size_t)(NL - 1) * HH,
                                  bet + (size_t)(NL - 1) * HH, 1,
                                  scsh + (size_t)NL * 256);
    k_bnapply<<<(NN * 64 + 255) / 256, 256, 0, stream>>>(h2, scsh + (size_t)NL * 256, xh);
    k_final<<<(NE * 16 + 255) / 256, 256, 0, stream>>>(xh, ei, fcw, fcb, out);
}

// Round 15
// 679.003 us; speedup vs baseline: 2.3534x; 2.3534x over previous
//
#include <hip/hip_runtime.h>

#define NN 100000
#define NE 600000
#define HH 128
#define NL 5
#define BN_EPS 1e-5f
#define NB 391    // (NN+255)/256
#define NGB 25000 // gather blocks = NN*64/256 (exact)
#define SR1B 625  // sred1 blocks
#define SR1R 40   // rows per sred1 block (625*40 = 25000 exact)
#define L2B 32    // sred2 blocks
#define SR2R 20   // rows per sred2 block (32*20 = 640 >= 625, masked)

typedef float f4 __attribute__((ext_vector_type(4)));
typedef float f2 __attribute__((ext_vector_type(2)));
typedef _Float16 h8 __attribute__((ext_vector_type(8)));
typedef _Float16 h2x __attribute__((ext_vector_type(2)));

// ---------------- edge-index dtype probe + normalize to int32 ----------------
__global__ void k_probe(const unsigned long long* __restrict__ e, int* __restrict__ flag) {
    if (blockIdx.x == 0 && threadIdx.x == 0) {
        int ok = 1;
        for (int i = 0; i < 64; ++i)
            if (e[i] >= (unsigned long long)NN) ok = 0;
        *flag = ok; // 1 => int64, 0 => int32
    }
}

__global__ void k_convert(const void* __restrict__ src, const int* __restrict__ flag,
                          int* __restrict__ dst) {
    int i = blockIdx.x * 256 + threadIdx.x;
    if (i >= 2 * NE) return;
    if (*flag) dst[i] = (int)((const long long*)src)[i];
    else       dst[i] = ((const int*)src)[i];
}

__global__ void k_zero(int* __restrict__ p, int n) {
    int i = blockIdx.x * 256 + threadIdx.x;
    if (i < n) p[i] = 0;
}

// ---------------- degree / dinv ----------------
__global__ void k_count_deg(const int* __restrict__ col, int* __restrict__ degi) {
    int e = blockIdx.x * 256 + threadIdx.x;
    if (e < NE) atomicAdd(&degi[col[e]], 1);
}

__global__ void k_dinv(const int* __restrict__ degi, float* __restrict__ dinv) {
    int i = blockIdx.x * 256 + threadIdx.x;
    if (i < NN) dinv[i] = rsqrtf((float)degi[i] + 1.0f);
}

// ---------------- prefix scan ----------------
__global__ __launch_bounds__(256) void k_scan1(const int* __restrict__ degi,
                                               int* __restrict__ incl,
                                               int* __restrict__ blocksums) {
    __shared__ int sd[256];
    int tid = threadIdx.x;
    int i = blockIdx.x * 256 + tid;
    int v = (i < NN) ? degi[i] : 0;
    sd[tid] = v;
    __syncthreads();
#pragma unroll
    for (int off = 1; off < 256; off <<= 1) {
        int t = (tid >= off) ? sd[tid - off] : 0;
        __syncthreads();
        sd[tid] += t;
        __syncthreads();
    }
    if (i < NN) incl[i] = sd[tid];
    if (tid == 255) blocksums[blockIdx.x] = sd[255];
}

__global__ __launch_bounds__(512) void k_scan2(const int* __restrict__ blocksums,
                                               int* __restrict__ blockoffs) {
    __shared__ int sd[512];
    int tid = threadIdx.x;
    int v = (tid < NB) ? blocksums[tid] : 0;
    sd[tid] = v;
    __syncthreads();
#pragma unroll
    for (int off = 1; off < 512; off <<= 1) {
        int t = (tid >= off) ? sd[tid - off] : 0;
        __syncthreads();
        sd[tid] += t;
        __syncthreads();
    }
    if (tid < NB) blockoffs[tid] = sd[tid] - v;
}

__global__ void k_scan3(const int* __restrict__ incl, const int* __restrict__ degi,
                        const int* __restrict__ blockoffs,
                        int* __restrict__ offsets, int* __restrict__ cursor) {
    int i = blockIdx.x * 256 + threadIdx.x;
    if (i >= NN) return;
    offsets[i] = incl[i] - degi[i] + blockoffs[blockIdx.x];
    cursor[i] = 0;
}

__global__ void k_scatter(const int* __restrict__ ei, const float* __restrict__ dinv,
                          const int* __restrict__ offsets, int* __restrict__ cursor,
                          int2* __restrict__ csr) {
    int e = blockIdx.x * 256 + threadIdx.x;
    if (e >= NE) return;
    int r = ei[e], c = ei[NE + e];
    int pos = offsets[c] + atomicAdd(&cursor[c], 1);
    int2 v;
    v.x = r;
    v.y = __float_as_int(dinv[r] * dinv[c]);
    csr[pos] = v;
}

// ---- transpose + split-cast weights: Wt{hi,lo}[l][n][k] from W[l][k][n] (fp32) ----
__global__ void k_wt(const float* __restrict__ W, _Float16* __restrict__ Wt_hi,
                     _Float16* __restrict__ Wt_lo) {
    int gid = blockIdx.x * 256 + threadIdx.x; // over NL*128*128
    if (gid >= NL * HH * HH) return;
    int l = gid >> 14;
    int rem = gid & 16383;
    int n = rem >> 7;
    int k = rem & 127;
    float w = W[l * HH * HH + k * HH + n];
    _Float16 hi = (_Float16)w;
    _Float16 lo = (_Float16)(w - (float)hi);
    Wt_hi[gid] = hi;
    Wt_lo[gid] = lo;
}

// ---- BN scale/shift for the final bnapply (sums 32 level2 rows) ----
__global__ void k_prep(const float* __restrict__ level2, const float* __restrict__ gamma,
                       const float* __restrict__ beta, float* __restrict__ scsh) {
    int k = threadIdx.x; // 128 threads
    float s = 0.0f, q = 0.0f;
#pragma unroll
    for (int b = 0; b < L2B; ++b) {
        s += level2[(size_t)b * 256 + k];
        q += level2[(size_t)b * 256 + 128 + k];
    }
    const float inv_n = 1.0f / (float)NN;
    float mean = s * inv_n;
    float var  = q * inv_n - mean * mean;
    float sc = gamma[k] * rsqrtf(var + BN_EPS);
    float sh = beta[k] - mean * sc;
    scsh[k] = sc;
    scsh[128 + k] = sh;
}

// ---------------- fused GEMM: h1 = relu?(bn(A)) @ W, split-fp16 MFMA, fp32 I/O ------
// BN prep fused into the prologue: threads 0-127 sum the 32 level2 rows (L2-hot)
// while all 256 threads stage weights. 65KB LDS -> 2 blocks/CU (130 <= 160KB).
// 256-row tile/block (391 blocks = single dispatch round).
// Swapped-operand MFMA: D = W^T·X^T = C^T => f4 C-stores.
// h1 = Xhi@Whi + Xhi@Wlo + Xlo@Whi  (error ~2^-22 rel; effectively fp32)
__global__ __launch_bounds__(256) void k_gemm(const float* __restrict__ A,
                                              const _Float16* __restrict__ Wt_hi,
                                              const _Float16* __restrict__ Wt_lo,
                                              const float* __restrict__ level2,
                                              const float* __restrict__ gamma,
                                              const float* __restrict__ beta,
                                              int mode, float negmul,
                                              float* __restrict__ C) {
    __shared__ _Float16 sBH[16384];  // 32 KB
    __shared__ _Float16 sBL[16384];  // 32 KB
    __shared__ float s_sc[128], s_sh[128];
    const int tid = threadIdx.x;

    if (tid < 128) {
        float sc = 1.0f, sh = 0.0f;
        if (mode) {
            float s = 0.0f, q = 0.0f;
#pragma unroll
            for (int b = 0; b < L2B; ++b) {
                s += level2[(size_t)b * 256 + tid];
                q += level2[(size_t)b * 256 + 128 + tid];
            }
            const float inv_n = 1.0f / (float)NN;
            float mean = s * inv_n;
            float var  = q * inv_n - mean * mean;
            sc = gamma[tid] * rsqrtf(var + BN_EPS);
            sh = beta[tid] - mean * sc;
        }
        s_sc[tid] = sc;
        s_sh[tid] = sh;
    }

#pragma unroll
    for (int it = 0; it < 8; ++it) {
        int g  = it * 256 + tid;
        int rr = g & 15;
        int kg = (g >> 4) & 3;
        int kc = (g >> 6) & 3;
        int n  = g >> 8;
        int glob = (n * 16 + rr) * HH + kc * 32 + kg * 8;
        *reinterpret_cast<h8*>(&sBH[g * 8]) = *reinterpret_cast<const h8*>(Wt_hi + glob);
        *reinterpret_cast<h8*>(&sBL[g * 8]) = *reinterpret_cast<const h8*>(Wt_lo + glob);
    }
    __syncthreads();

    const int wave = tid >> 6;
    const int lane = tid & 63;
    const int r    = lane & 15;
    const int kg   = lane >> 4;        // 0..3
    const int row0 = blockIdx.x * 256 + wave * 64;

    f4 acc[4][8];
#pragma unroll
    for (int m = 0; m < 4; ++m)
#pragma unroll
        for (int n = 0; n < 8; ++n) acc[m][n] = (f4)0.0f;

    const float* Ap[4];
#pragma unroll
    for (int m = 0; m < 4; ++m) {
        int ra = row0 + m * 16 + r;
        if (ra >= NN) ra = NN - 1;
        Ap[m] = A + (size_t)ra * HH + kg * 8;
    }

#pragma unroll
    for (int kc = 0; kc < 4; ++kc) {
        const int k0 = kc * 32 + kg * 8;
        f4 scA = *reinterpret_cast<const f4*>(&s_sc[k0]);
        f4 scB = *reinterpret_cast<const f4*>(&s_sc[k0 + 4]);
        f4 shA = *reinterpret_cast<const f4*>(&s_sh[k0]);
        f4 shB = *reinterpret_cast<const f4*>(&s_sh[k0 + 4]);
        h8 ahi[4], alo[4];
#pragma unroll
        for (int m = 0; m < 4; ++m) {
            f4 ax = *reinterpret_cast<const f4*>(Ap[m] + kc * 32);
            f4 ay = *reinterpret_cast<const f4*>(Ap[m] + kc * 32 + 4);
#pragma unroll
            for (int j = 0; j < 4; ++j) {
                float t;
                t = fmaf(ax[j], scA[j], shA[j]); t = fmaxf(t, t * negmul);
                ahi[m][j] = (_Float16)t;      alo[m][j] = (_Float16)(t - (float)ahi[m][j]);
                t = fmaf(ay[j], scB[j], shB[j]); t = fmaxf(t, t * negmul);
                ahi[m][j + 4] = (_Float16)t;  alo[m][j + 4] = (_Float16)(t - (float)ahi[m][j + 4]);
            }
        }
#pragma unroll
        for (int n = 0; n < 8; ++n) {
            int g = n * 256 + kc * 64 + lane;
            h8 bh = *reinterpret_cast<const h8*>(&sBH[g * 8]);
            h8 bl = *reinterpret_cast<const h8*>(&sBL[g * 8]);
#pragma unroll
            for (int m = 0; m < 4; ++m) {
                acc[m][n] = __builtin_amdgcn_mfma_f32_16x16x32_f16(bh, ahi[m], acc[m][n], 0, 0, 0);
                acc[m][n] = __builtin_amdgcn_mfma_f32_16x16x32_f16(bl, ahi[m], acc[m][n], 0, 0, 0);
                acc[m][n] = __builtin_amdgcn_mfma_f32_16x16x32_f16(bh, alo[m], acc[m][n], 0, 0, 0);
            }
        }
    }

    // D^T mapping: lane (r,kg) holds C[row0 + m*16 + r][n*16 + kg*4 + i], i=0..3 -> f4
#pragma unroll
    for (int m = 0; m < 4; ++m) {
        int rr = row0 + m * 16 + r;
        if (rr < NN) {
            float* Crow = C + (size_t)rr * HH + kg * 4;
#pragma unroll
            for (int n = 0; n < 8; ++n)
                *reinterpret_cast<f4*>(Crow + n * 16) = acc[m][n];
        }
    }
}

// ------- gather aggregation (fp32) + fused BN partial stats -------
// One wave per node (round-11 proven config) + per-block coalesced partial write.
__global__ __launch_bounds__(256) void k_gather(const float* __restrict__ h1,
                                                const int* __restrict__ offsets,
                                                const int* __restrict__ degi,
                                                const int2* __restrict__ csr,
                                                const float* __restrict__ dinv,
                                                float* __restrict__ h2,
                                                float* __restrict__ partial) {
    __shared__ f2 ls[4][64];
    __shared__ f2 lss[4][64];
    int gid  = blockIdx.x * 256 + threadIdx.x;
    int node = gid >> 6;        // grid exact: node < NN always
    int lane = gid & 63;
    int wid  = threadIdx.x >> 6;
    float di = dinv[node];
    f2 acc0 = reinterpret_cast<const f2*>(h1 + (size_t)node * HH)[lane] * (di * di);
    f2 acc1 = (f2)0.0f, acc2 = (f2)0.0f, acc3 = (f2)0.0f;
    const int start = offsets[node];
    const int end   = start + degi[node];
    for (int b = start; b < end; b += 4) {
        int2 ce0 = csr[b];
        int2 ce1 = (b + 1 < end) ? csr[b + 1] : make_int2(0, 0);
        int2 ce2 = (b + 2 < end) ? csr[b + 2] : make_int2(0, 0);
        int2 ce3 = (b + 3 < end) ? csr[b + 3] : make_int2(0, 0);
        f2 v0 = reinterpret_cast<const f2*>(h1 + (size_t)ce0.x * HH)[lane];
        f2 v1 = reinterpret_cast<const f2*>(h1 + (size_t)ce1.x * HH)[lane];
        f2 v2 = reinterpret_cast<const f2*>(h1 + (size_t)ce2.x * HH)[lane];
        f2 v3 = reinterpret_cast<const f2*>(h1 + (size_t)ce3.x * HH)[lane];
        acc0 += v0 * __int_as_float(ce0.y);
        acc1 += v1 * __int_as_float(ce1.y);
        acc2 += v2 * __int_as_float(ce2.y);
        acc3 += v3 * __int_as_float(ce3.y);
    }
    acc0 += acc2;
    acc1 += acc3;
    acc0 += acc1;
    reinterpret_cast<f2*>(h2 + (size_t)node * HH)[lane] = acc0;

    // fused BN partial stats (no atomics)
    ls[wid][lane] = acc0;
    lss[wid][lane] = acc0 * acc0;
    __syncthreads();
    if (threadIdx.x < 64) {
        int c = threadIdx.x;
        f2 s = ls[0][c] + ls[1][c] + ls[2][c] + ls[3][c];
        f2 q = lss[0][c] + lss[1][c] + lss[2][c] + lss[3][c];
        f2* pp = reinterpret_cast<f2*>(partial + (size_t)blockIdx.x * 256);
        pp[c] = s;        // cols [0..127]: sum
        pp[64 + c] = q;   // cols [128..255]: sumsq
    }
}

// ------- stats level 1: 625 blocks x 40 rows, fully unrolled (40 loads in flight) ----
__global__ __launch_bounds__(256) void k_sred1(const float* __restrict__ partial,
                                               float* __restrict__ mid) {
    int c = threadIdx.x; // 256
    const float* base = partial + (size_t)blockIdx.x * SR1R * 256 + c;
    float s0 = 0.f, s1 = 0.f, s2 = 0.f, s3 = 0.f;
#pragma unroll
    for (int i = 0; i < SR1R; i += 4) {
        s0 += base[(size_t)(i + 0) * 256];
        s1 += base[(size_t)(i + 1) * 256];
        s2 += base[(size_t)(i + 2) * 256];
        s3 += base[(size_t)(i + 3) * 256];
    }
    mid[(size_t)blockIdx.x * 256 + c] = (s0 + s1) + (s2 + s3);
}

// ------- stats level 2: 32 blocks x 20 rows (masked), unrolled -------
__global__ __launch_bounds__(256) void k_sred2(const float* __restrict__ mid,
                                               float* __restrict__ level2) {
    int c = threadIdx.x; // 256
    int b0 = blockIdx.x * SR2R;
    float s = 0.0f;
#pragma unroll
    for (int i = 0; i < SR2R; ++i) {
        int b = b0 + i;
        if (b < SR1B) s += mid[(size_t)b * 256 + c];
    }
    level2[(size_t)blockIdx.x * 256 + c] = s;
}

// ------- final-layer BN apply + ReLU: fp32 h2 -> fp16 x5 (scsh input) -------
__global__ void k_bnapply(const float* __restrict__ h2, const float* __restrict__ scsh,
                          _Float16* __restrict__ xh) {
    int idx = blockIdx.x * 256 + threadIdx.x; // over NN*64 pairs
    if (idx >= NN * 64) return;
    int cp = idx & 63;
    float sc0 = scsh[2 * cp],       sc1 = scsh[2 * cp + 1];
    float sh0 = scsh[128 + 2 * cp], sh1 = scsh[128 + 2 * cp + 1];
    f2 v = reinterpret_cast<const f2*>(h2)[idx];
    float t0 = fmaf(v[0], sc0, sh0);
    float t1 = fmaf(v[1], sc1, sh1);
    t0 = fmaxf(t0, 0.0f);
    t1 = fmaxf(t1, 0.0f);
    h2x o;
    o[0] = (_Float16)t0;
    o[1] = (_Float16)t1;
    reinterpret_cast<h2x*>(xh)[idx] = o;
}

// ---------------- final: 16 lanes per edge, fp16 rows, fp32 math ----------------
__global__ __launch_bounds__(256) void k_final(const _Float16* __restrict__ x,
                                               const int* __restrict__ ei,
                                               const float* __restrict__ fcw,
                                               const float* __restrict__ fcb,
                                               float* __restrict__ out) {
    int gid  = blockIdx.x * 256 + threadIdx.x;
    int e    = gid >> 4;          // 16 lanes per edge
    int l16  = gid & 15;
    if (e >= NE) return;
    int a = ei[e];
    int b = ei[NE + e];
    h8 va = *reinterpret_cast<const h8*>(x + (size_t)a * HH + l16 * 8);
    h8 vb = *reinterpret_cast<const h8*>(x + (size_t)b * HH + l16 * 8);
    f4 w0 = *reinterpret_cast<const f4*>(fcw + l16 * 8);
    f4 w1 = *reinterpret_cast<const f4*>(fcw + l16 * 8 + 4);
    float p = 0.0f;
#pragma unroll
    for (int j = 0; j < 4; ++j) {
        p += (float)va[j] * (float)vb[j] * w0[j];
        p += (float)va[j + 4] * (float)vb[j + 4] * w1[j];
    }
#pragma unroll
    for (int off = 8; off > 0; off >>= 1) p += __shfl_xor(p, off, 64);
    if (l16 == 0) out[e] = 1.0f / (1.0f + expf(-(p + fcb[0])));
}

extern "C" void kernel_launch(void* const* d_in, const int* in_sizes, int n_in,
                              void* d_out, int out_size, void* d_ws, size_t ws_size,
                              hipStream_t stream) {
    const float* x   = (const float*)d_in[0];
    const void*  ei_raw = d_in[1];
    const float* cw  = (const float*)d_in[2];
    // d_in[3] = conv_b: cancels exactly through BatchNorm -> unused
    const float* gam = (const float*)d_in[4];
    const float* bet = (const float*)d_in[5];
    const float* fcw = (const float*)d_in[6];
    const float* fcb = (const float*)d_in[7];
    float* out = (float*)d_out;

    const size_t NH = (size_t)NN * HH;
    unsigned char* p = (unsigned char*)d_ws;
    float* h1 = (float*)p;       p += NH * 4;            // fp32 gemm out
    float* h2 = (float*)p;       p += NH * 4;            // fp32 aggregated
    _Float16* xh = (_Float16*)p; p += NH * 2;            // fp16 x5 for edge head
    _Float16* WtH = (_Float16*)p; p += (size_t)NL * HH * HH * 2;
    _Float16* WtL = (_Float16*)p; p += (size_t)NL * HH * HH * 2;
    int2*  csr   = (int2*)p;     p += (size_t)NE * 8;
    float* dinv  = (float*)p;    p += NN * 4;
    float* scsh  = (float*)p;    p += 256 * 4;
    float* partial = (float*)p;  p += (size_t)NGB * 256 * 4;  // 25.6 MB
    float* mid     = (float*)p;  p += (size_t)SR1B * 256 * 4; // 640 KB
    float* level2  = (float*)p;  p += (size_t)L2B * 256 * 4;  // 32 KB
    int*   ei    = (int*)p;      p += (size_t)2 * NE * 4;
    int*   degi  = (int*)p;      p += NN * 4;
    int*   incl  = (int*)p;      p += NN * 4;
    int*   offsets = (int*)p;    p += NN * 4;
    int*   cursor  = (int*)p;    p += NN * 4;
    int*   blocksums = (int*)p;  p += NB * 4;
    int*   blockoffs = (int*)p;  p += NB * 4;
    int*   flag  = (int*)p;

    // normalize edge index dtype to int32
    k_probe<<<1, 64, 0, stream>>>((const unsigned long long*)ei_raw, flag);
    k_convert<<<(2 * NE + 255) / 256, 256, 0, stream>>>(ei_raw, flag, ei);

    // degrees -> dinv; CSR build
    k_zero<<<(NN + 255) / 256, 256, 0, stream>>>(degi, NN);
    k_count_deg<<<(NE + 255) / 256, 256, 0, stream>>>(ei + NE, degi);
    k_dinv<<<(NN + 255) / 256, 256, 0, stream>>>(degi, dinv);
    k_scan1<<<NB, 256, 0, stream>>>(degi, incl, blocksums);
    k_scan2<<<1, 512, 0, stream>>>(blocksums, blockoffs);
    k_scan3<<<NB, 256, 0, stream>>>(incl, degi, blockoffs, offsets, cursor);
    k_scatter<<<(NE + 255) / 256, 256, 0, stream>>>(ei, dinv, offsets, cursor, csr);

    // split weights (fp16 hi/lo, transposed)
    k_wt<<<(NL * HH * HH + 255) / 256, 256, 0, stream>>>(cw, WtH, WtL);

    for (int l = 0; l < NL; ++l) {
        k_gemm<<<(NN + 255) / 256, 256, 0, stream>>>(
            (l == 0) ? x : h2, WtH + (size_t)l * HH * HH, WtL + (size_t)l * HH * HH,
            level2,
            (l == 0) ? gam : gam + (size_t)(l - 1) * HH,
            (l == 0) ? bet : bet + (size_t)(l - 1) * HH,
            (l == 0) ? 0 : 1, (l == 0) ? 1.0f : 0.0f, h1);
        k_gather<<<NGB, 256, 0, stream>>>(h1, offsets, degi, csr, dinv, h2, partial);
        k_sred1<<<SR1B, 256, 0, stream>>>(partial, mid);
        k_sred2<<<L2B, 256, 0, stream>>>(mid, level2);
    }
    // layer-5 scsh, then materialize x5 (fp16) for the edge head
    k_prep<<<1, 128, 0, stream>>>(level2, gam + (size_t)(NL - 1) * HH,
                                  bet + (size_t)(NL - 1) * HH, scsh);
    k_bnapply<<<(NN * 64 + 255) / 256, 256, 0, stream>>>(h2, scsh, xh);
    k_final<<<(NE * 16 + 255) / 256, 256, 0, stream>>>(xh, ei, fcw, fcb, out);
}

// Round 17
// 672.251 us; speedup vs baseline: 2.3770x; 1.0100x over previous
//
#include <hip/hip_runtime.h>

#define NN 100000
#define NE 600000
#define HH 128
#define NL 5
#define BN_EPS 1e-5f
#define NB 391    // (NN+255)/256
#define NGB 25000 // gather blocks = NN*64/256 (exact)
#define SR1B 625  // sred1 blocks
#define SR1R 40   // rows per sred1 block (625*40 = 25000 exact)
#define L2B 32    // sred2 blocks
#define SR2R 20   // rows per sred2 block (32*20 = 640 >= 625, masked)

typedef float f4 __attribute__((ext_vector_type(4)));
typedef float f2 __attribute__((ext_vector_type(2)));
typedef _Float16 h8 __attribute__((ext_vector_type(8)));
typedef _Float16 h2x __attribute__((ext_vector_type(2)));
typedef __fp16 p16x2 __attribute__((ext_vector_type(2)));  // cvt_pkrtz result type

// ---------------- edge-index dtype probe + normalize to int32 ----------------
__global__ void k_probe(const unsigned long long* __restrict__ e, int* __restrict__ flag) {
    if (blockIdx.x == 0 && threadIdx.x == 0) {
        int ok = 1;
        for (int i = 0; i < 64; ++i)
            if (e[i] >= (unsigned long long)NN) ok = 0;
        *flag = ok; // 1 => int64, 0 => int32
    }
}

__global__ void k_convert(const void* __restrict__ src, const int* __restrict__ flag,
                          int* __restrict__ dst) {
    int i = blockIdx.x * 256 + threadIdx.x;
    if (i >= 2 * NE) return;
    if (*flag) dst[i] = (int)((const long long*)src)[i];
    else       dst[i] = ((const int*)src)[i];
}

__global__ void k_zero(int* __restrict__ p, int n) {
    int i = blockIdx.x * 256 + threadIdx.x;
    if (i < n) p[i] = 0;
}

// ---------------- degree / dinv ----------------
__global__ void k_count_deg(const int* __restrict__ col, int* __restrict__ degi) {
    int e = blockIdx.x * 256 + threadIdx.x;
    if (e < NE) atomicAdd(&degi[col[e]], 1);
}

__global__ void k_dinv(const int* __restrict__ degi, float* __restrict__ dinv) {
    int i = blockIdx.x * 256 + threadIdx.x;
    if (i < NN) dinv[i] = rsqrtf((float)degi[i] + 1.0f);
}

// ---------------- prefix scan ----------------
__global__ __launch_bounds__(256) void k_scan1(const int* __restrict__ degi,
                                               int* __restrict__ incl,
                                               int* __restrict__ blocksums) {
    __shared__ int sd[256];
    int tid = threadIdx.x;
    int i = blockIdx.x * 256 + tid;
    int v = (i < NN) ? degi[i] : 0;
    sd[tid] = v;
    __syncthreads();
#pragma unroll
    for (int off = 1; off < 256; off <<= 1) {
        int t = (tid >= off) ? sd[tid - off] : 0;
        __syncthreads();
        sd[tid] += t;
        __syncthreads();
    }
    if (i < NN) incl[i] = sd[tid];
    if (tid == 255) blocksums[blockIdx.x] = sd[255];
}

__global__ __launch_bounds__(512) void k_scan2(const int* __restrict__ blocksums,
                                               int* __restrict__ blockoffs) {
    __shared__ int sd[512];
    int tid = threadIdx.x;
    int v = (tid < NB) ? blocksums[tid] : 0;
    sd[tid] = v;
    __syncthreads();
#pragma unroll
    for (int off = 1; off < 512; off <<= 1) {
        int t = (tid >= off) ? sd[tid - off] : 0;
        __syncthreads();
        sd[tid] += t;
        __syncthreads();
    }
    if (tid < NB) blockoffs[tid] = sd[tid] - v;
}

__global__ void k_scan3(const int* __restrict__ incl, const int* __restrict__ degi,
                        const int* __restrict__ blockoffs,
                        int* __restrict__ offsets, int* __restrict__ cursor) {
    int i = blockIdx.x * 256 + threadIdx.x;
    if (i >= NN) return;
    offsets[i] = incl[i] - degi[i] + blockoffs[blockIdx.x];
    cursor[i] = 0;
}

__global__ void k_scatter(const int* __restrict__ ei, const float* __restrict__ dinv,
                          const int* __restrict__ offsets, int* __restrict__ cursor,
                          int2* __restrict__ csr) {
    int e = blockIdx.x * 256 + threadIdx.x;
    if (e >= NE) return;
    int r = ei[e], c = ei[NE + e];
    int pos = offsets[c] + atomicAdd(&cursor[c], 1);
    int2 v;
    v.x = r;
    v.y = __float_as_int(dinv[r] * dinv[c]);
    csr[pos] = v;
}

// ---- transpose + split-cast weights: Wt{hi,lo}[l][n][k] from W[l][k][n] (fp32) ----
__global__ void k_wt(const float* __restrict__ W, _Float16* __restrict__ Wt_hi,
                     _Float16* __restrict__ Wt_lo) {
    int gid = blockIdx.x * 256 + threadIdx.x; // over NL*128*128
    if (gid >= NL * HH * HH) return;
    int l = gid >> 14;
    int rem = gid & 16383;
    int n = rem >> 7;
    int k = rem & 127;
    float w = W[l * HH * HH + k * HH + n];
    _Float16 hi = (_Float16)w;
    _Float16 lo = (_Float16)(w - (float)hi);
    Wt_hi[gid] = hi;
    Wt_lo[gid] = lo;
}

// ---- BN scale/shift for the final bnapply (sums 32 level2 rows) ----
__global__ void k_prep(const float* __restrict__ level2, const float* __restrict__ gamma,
                       const float* __restrict__ beta, float* __restrict__ scsh) {
    int k = threadIdx.x; // 128 threads
    float s = 0.0f, q = 0.0f;
#pragma unroll
    for (int b = 0; b < L2B; ++b) {
        s += level2[(size_t)b * 256 + k];
        q += level2[(size_t)b * 256 + 128 + k];
    }
    const float inv_n = 1.0f / (float)NN;
    float mean = s * inv_n;
    float var  = q * inv_n - mean * mean;
    float sc = gamma[k] * rsqrtf(var + BN_EPS);
    float sh = beta[k] - mean * sc;
    scsh[k] = sc;
    scsh[128 + k] = sh;
}

// ---------------- fused GEMM: h1 = relu?(bn(A)) @ W, split-fp16 MFMA, fp32 I/O ------
// FIRST=true: layer 0, A used as-is (no BN/relu). FIRST=false: BN prep fused in
// prologue (threads 0-127 sum 32 level2 rows), relu via fmaxf(t,0), split via
// v_cvt_pkrtz (2 f32->f16 per inst; RTZ on hi is corrected by lo).
// 256-row tile/block (391 blocks). Swapped-operand MFMA: D = W^T·X^T = C^T.
// h1 = Xhi@Whi + Xhi@Wlo + Xlo@Whi  (error ~2^-22 rel; effectively fp32)
template<bool FIRST>
__global__ __launch_bounds__(256) void k_gemm(const float* __restrict__ A,
                                              const _Float16* __restrict__ Wt_hi,
                                              const _Float16* __restrict__ Wt_lo,
                                              const float* __restrict__ level2,
                                              const float* __restrict__ gamma,
                                              const float* __restrict__ beta,
                                              float* __restrict__ C) {
    __shared__ _Float16 sBH[16384];  // 32 KB
    __shared__ _Float16 sBL[16384];  // 32 KB
    __shared__ float s_sc[128], s_sh[128];
    const int tid = threadIdx.x;

    if (!FIRST && tid < 128) {
        float s = 0.0f, q = 0.0f;
#pragma unroll
        for (int b = 0; b < L2B; ++b) {
            s += level2[(size_t)b * 256 + tid];
            q += level2[(size_t)b * 256 + 128 + tid];
        }
        const float inv_n = 1.0f / (float)NN;
        float mean = s * inv_n;
        float var  = q * inv_n - mean * mean;
        float sc = gamma[tid] * rsqrtf(var + BN_EPS);
        s_sc[tid] = sc;
        s_sh[tid] = beta[tid] - mean * sc;
    }

#pragma unroll
    for (int it = 0; it < 8; ++it) {
        int g  = it * 256 + tid;
        int rr = g & 15;
        int kg = (g >> 4) & 3;
        int kc = (g >> 6) & 3;
        int n  = g >> 8;
        int glob = (n * 16 + rr) * HH + kc * 32 + kg * 8;
        *reinterpret_cast<h8*>(&sBH[g * 8]) = *reinterpret_cast<const h8*>(Wt_hi + glob);
        *reinterpret_cast<h8*>(&sBL[g * 8]) = *reinterpret_cast<const h8*>(Wt_lo + glob);
    }
    __syncthreads();

    const int wave = tid >> 6;
    const int lane = tid & 63;
    const int r    = lane & 15;
    const int kg   = lane >> 4;        // 0..3
    const int row0 = blockIdx.x * 256 + wave * 64;

    f4 acc[4][8];
#pragma unroll
    for (int m = 0; m < 4; ++m)
#pragma unroll
        for (int n = 0; n < 8; ++n) acc[m][n] = (f4)0.0f;

    const float* Ap[4];
#pragma unroll
    for (int m = 0; m < 4; ++m) {
        int ra = row0 + m * 16 + r;
        if (ra >= NN) ra = NN - 1;
        Ap[m] = A + (size_t)ra * HH + kg * 8;
    }

#pragma unroll
    for (int kc = 0; kc < 4; ++kc) {
        const int k0 = kc * 32 + kg * 8;
        f4 scA, scB, shA, shB;
        if (!FIRST) {
            scA = *reinterpret_cast<const f4*>(&s_sc[k0]);
            scB = *reinterpret_cast<const f4*>(&s_sc[k0 + 4]);
            shA = *reinterpret_cast<const f4*>(&s_sh[k0]);
            shB = *reinterpret_cast<const f4*>(&s_sh[k0 + 4]);
        }
        h8 ahi[4], alo[4];
#pragma unroll
        for (int m = 0; m < 4; ++m) {
            f4 ax = *reinterpret_cast<const f4*>(Ap[m] + kc * 32);
            f4 ay = *reinterpret_cast<const f4*>(Ap[m] + kc * 32 + 4);
            float t[8];
#pragma unroll
            for (int j = 0; j < 4; ++j) {
                if (FIRST) {
                    t[j]     = ax[j];
                    t[j + 4] = ay[j];
                } else {
                    t[j]     = fmaxf(fmaf(ax[j], scA[j], shA[j]), 0.0f);
                    t[j + 4] = fmaxf(fmaf(ay[j], scB[j], shB[j]), 0.0f);
                }
            }
#pragma unroll
            for (int p2 = 0; p2 < 4; ++p2) {
                p16x2 hi2 = __builtin_amdgcn_cvt_pkrtz(t[2 * p2], t[2 * p2 + 1]);
                p16x2 lo2 = __builtin_amdgcn_cvt_pkrtz(t[2 * p2] - (float)hi2[0],
                                                       t[2 * p2 + 1] - (float)hi2[1]);
                ahi[m][2 * p2]     = (_Float16)hi2[0];
                ahi[m][2 * p2 + 1] = (_Float16)hi2[1];
                alo[m][2 * p2]     = (_Float16)lo2[0];
                alo[m][2 * p2 + 1] = (_Float16)lo2[1];
            }
        }
#pragma unroll
        for (int n = 0; n < 8; ++n) {
            int g = n * 256 + kc * 64 + lane;
            h8 bh = *reinterpret_cast<const h8*>(&sBH[g * 8]);
            h8 bl = *reinterpret_cast<const h8*>(&sBL[g * 8]);
#pragma unroll
            for (int m = 0; m < 4; ++m) {
                acc[m][n] = __builtin_amdgcn_mfma_f32_16x16x32_f16(bh, ahi[m], acc[m][n], 0, 0, 0);
                acc[m][n] = __builtin_amdgcn_mfma_f32_16x16x32_f16(bl, ahi[m], acc[m][n], 0, 0, 0);
                acc[m][n] = __builtin_amdgcn_mfma_f32_16x16x32_f16(bh, alo[m], acc[m][n], 0, 0, 0);
            }
        }
    }

    // D^T mapping: lane (r,kg) holds C[row0 + m*16 + r][n*16 + kg*4 + i], i=0..3 -> f4
#pragma unroll
    for (int m = 0; m < 4; ++m) {
        int rr = row0 + m * 16 + r;
        if (rr < NN) {
            float* Crow = C + (size_t)rr * HH + kg * 4;
#pragma unroll
            for (int n = 0; n < 8; ++n)
                *reinterpret_cast<f4*>(Crow + n * 16) = acc[m][n];
        }
    }
}

// ------- gather aggregation (fp32) + fused BN partial stats -------
// One wave per node (round-11 proven config) + per-block coalesced partial write.
__global__ __launch_bounds__(256) void k_gather(const float* __restrict__ h1,
                                                const int* __restrict__ offsets,
                                                const int* __restrict__ degi,
                                                const int2* __restrict__ csr,
                                                const float* __restrict__ dinv,
                                                float* __restrict__ h2,
                                                float* __restrict__ partial) {
    __shared__ f2 ls[4][64];
    __shared__ f2 lss[4][64];
    int gid  = blockIdx.x * 256 + threadIdx.x;
    int node = gid >> 6;        // grid exact: node < NN always
    int lane = gid & 63;
    int wid  = threadIdx.x >> 6;
    float di = dinv[node];
    f2 acc0 = reinterpret_cast<const f2*>(h1 + (size_t)node * HH)[lane] * (di * di);
    f2 acc1 = (f2)0.0f, acc2 = (f2)0.0f, acc3 = (f2)0.0f;
    const int start = offsets[node];
    const int end   = start + degi[node];
    for (int b = start; b < end; b += 4) {
        int2 ce0 = csr[b];
        int2 ce1 = (b + 1 < end) ? csr[b + 1] : make_int2(0, 0);
        int2 ce2 = (b + 2 < end) ? csr[b + 2] : make_int2(0, 0);
        int2 ce3 = (b + 3 < end) ? csr[b + 3] : make_int2(0, 0);
        f2 v0 = reinterpret_cast<const f2*>(h1 + (size_t)ce0.x * HH)[lane];
        f2 v1 = reinterpret_cast<const f2*>(h1 + (size_t)ce1.x * HH)[lane];
        f2 v2 = reinterpret_cast<const f2*>(h1 + (size_t)ce2.x * HH)[lane];
        f2 v3 = reinterpret_cast<const f2*>(h1 + (size_t)ce3.x * HH)[lane];
        acc0 += v0 * __int_as_float(ce0.y);
        acc1 += v1 * __int_as_float(ce1.y);
        acc2 += v2 * __int_as_float(ce2.y);
        acc3 += v3 * __int_as_float(ce3.y);
    }
    acc0 += acc2;
    acc1 += acc3;
    acc0 += acc1;
    reinterpret_cast<f2*>(h2 + (size_t)node * HH)[lane] = acc0;

    // fused BN partial stats (no atomics)
    ls[wid][lane] = acc0;
    lss[wid][lane] = acc0 * acc0;
    __syncthreads();
    if (threadIdx.x < 64) {
        int c = threadIdx.x;
        f2 s = ls[0][c] + ls[1][c] + ls[2][c] + ls[3][c];
        f2 q = lss[0][c] + lss[1][c] + lss[2][c] + lss[3][c];
        f2* pp = reinterpret_cast<f2*>(partial + (size_t)blockIdx.x * 256);
        pp[c] = s;        // cols [0..127]: sum
        pp[64 + c] = q;   // cols [128..255]: sumsq
    }
}

// ------- stats level 1: 625 blocks x 40 rows, fully unrolled (40 loads in flight) ----
__global__ __launch_bounds__(256) void k_sred1(const float* __restrict__ partial,
                                               float* __restrict__ mid) {
    int c = threadIdx.x; // 256
    const float* base = partial + (size_t)blockIdx.x * SR1R * 256 + c;
    float s0 = 0.f, s1 = 0.f, s2 = 0.f, s3 = 0.f;
#pragma unroll
    for (int i = 0; i < SR1R; i += 4) {
        s0 += base[(size_t)(i + 0) * 256];
        s1 += base[(size_t)(i + 1) * 256];
        s2 += base[(size_t)(i + 2) * 256];
        s3 += base[(size_t)(i + 3) * 256];
    }
    mid[(size_t)blockIdx.x * 256 + c] = (s0 + s1) + (s2 + s3);
}

// ------- stats level 2: 32 blocks x 20 rows (masked), unrolled -------
__global__ __launch_bounds__(256) void k_sred2(const float* __restrict__ mid,
                                               float* __restrict__ level2) {
    int c = threadIdx.x; // 256
    int b0 = blockIdx.x * SR2R;
    float s = 0.0f;
#pragma unroll
    for (int i = 0; i < SR2R; ++i) {
        int b = b0 + i;
        if (b < SR1B) s += mid[(size_t)b * 256 + c];
    }
    level2[(size_t)blockIdx.x * 256 + c] = s;
}

// ------- final-layer BN apply + ReLU: fp32 h2 -> fp16 x5 (scsh input) -------
__global__ void k_bnapply(const float* __restrict__ h2, const float* __restrict__ scsh,
                          _Float16* __restrict__ xh) {
    int idx = blockIdx.x * 256 + threadIdx.x; // over NN*64 pairs
    if (idx >= NN * 64) return;
    int cp = idx & 63;
    float sc0 = scsh[2 * cp],       sc1 = scsh[2 * cp + 1];
    float sh0 = scsh[128 + 2 * cp], sh1 = scsh[128 + 2 * cp + 1];
    f2 v = reinterpret_cast<const f2*>(h2)[idx];
    float t0 = fmaf(v[0], sc0, sh0);
    float t1 = fmaf(v[1], sc1, sh1);
    t0 = fmaxf(t0, 0.0f);
    t1 = fmaxf(t1, 0.0f);
    h2x o;
    o[0] = (_Float16)t0;
    o[1] = (_Float16)t1;
    reinterpret_cast<h2x*>(xh)[idx] = o;
}

// ---------------- final: 16 lanes per edge, fp16 rows, fp32 math ----------------
__global__ __launch_bounds__(256) void k_final(const _Float16* __restrict__ x,
                                               const int* __restrict__ ei,
                                               const float* __restrict__ fcw,
                                               const float* __restrict__ fcb,
                                               float* __restrict__ out) {
    int gid  = blockIdx.x * 256 + threadIdx.x;
    int e    = gid >> 4;          // 16 lanes per edge
    int l16  = gid & 15;
    if (e >= NE) return;
    int a = ei[e];
    int b = ei[NE + e];
    h8 va = *reinterpret_cast<const h8*>(x + (size_t)a * HH + l16 * 8);
    h8 vb = *reinterpret_cast<const h8*>(x + (size_t)b * HH + l16 * 8);
    f4 w0 = *reinterpret_cast<const f4*>(fcw + l16 * 8);
    f4 w1 = *reinterpret_cast<const f4*>(fcw + l16 * 8 + 4);
    float p = 0.0f;
#pragma unroll
    for (int j = 0; j < 4; ++j) {
        p += (float)va[j] * (float)vb[j] * w0[j];
        p += (float)va[j + 4] * (float)vb[j + 4] * w1[j];
    }
#pragma unroll
    for (int off = 8; off > 0; off >>= 1) p += __shfl_xor(p, off, 64);
    if (l16 == 0) out[e] = 1.0f / (1.0f + expf(-(p + fcb[0])));
}

extern "C" void kernel_launch(void* const* d_in, const int* in_sizes, int n_in,
                              void* d_out, int out_size, void* d_ws, size_t ws_size,
                              hipStream_t stream) {
    const float* x   = (const float*)d_in[0];
    const void*  ei_raw = d_in[1];
    const float* cw  = (const float*)d_in[2];
    // d_in[3] = conv_b: cancels exactly through BatchNorm -> unused
    const float* gam = (const float*)d_in[4];
    const float* bet = (const float*)d_in[5];
    const float* fcw = (const float*)d_in[6];
    const float* fcb = (const float*)d_in[7];
    float* out = (float*)d_out;

    const size_t NH = (size_t)NN * HH;
    unsigned char* p = (unsigned char*)d_ws;
    float* h1 = (float*)p;       p += NH * 4;            // fp32 gemm out
    float* h2 = (float*)p;       p += NH * 4;            // fp32 aggregated
    _Float16* xh = (_Float16*)p; p += NH * 2;            // fp16 x5 for edge head
    _Float16* WtH = (_Float16*)p; p += (size_t)NL * HH * HH * 2;
    _Float16* WtL = (_Float16*)p; p += (size_t)NL * HH * HH * 2;
    int2*  csr   = (int2*)p;     p += (size_t)NE * 8;
    float* dinv  = (float*)p;    p += NN * 4;
    float* scsh  = (float*)p;    p += 256 * 4;
    float* partial = (float*)p;  p += (size_t)NGB * 256 * 4;  // 25.6 MB
    float* mid     = (float*)p;  p += (size_t)SR1B * 256 * 4; // 640 KB
    float* level2  = (float*)p;  p += (size_t)L2B * 256 * 4;  // 32 KB
    int*   ei    = (int*)p;      p += (size_t)2 * NE * 4;
    int*   degi  = (int*)p;      p += NN * 4;
    int*   incl  = (int*)p;      p += NN * 4;
    int*   offsets = (int*)p;    p += NN * 4;
    int*   cursor  = (int*)p;    p += NN * 4;
    int*   blocksums = (int*)p;  p += NB * 4;
    int*   blockoffs = (int*)p;  p += NB * 4;
    int*   flag  = (int*)p;

    // normalize edge index dtype to int32
    k_probe<<<1, 64, 0, stream>>>((const unsigned long long*)ei_raw, flag);
    k_convert<<<(2 * NE + 255) / 256, 256, 0, stream>>>(ei_raw, flag, ei);

    // degrees -> dinv; CSR build
    k_zero<<<(NN + 255) / 256, 256, 0, stream>>>(degi, NN);
    k_count_deg<<<(NE + 255) / 256, 256, 0, stream>>>(ei + NE, degi);
    k_dinv<<<(NN + 255) / 256, 256, 0, stream>>>(degi, dinv);
    k_scan1<<<NB, 256, 0, stream>>>(degi, incl, blocksums);
    k_scan2<<<1, 512, 0, stream>>>(blocksums, blockoffs);
    k_scan3<<<NB, 256, 0, stream>>>(incl, degi, blockoffs, offsets, cursor);
    k_scatter<<<(NE + 255) / 256, 256, 0, stream>>>(ei, dinv, offsets, cursor, csr);

    // split weights (fp16 hi/lo, transposed)
    k_wt<<<(NL * HH * HH + 255) / 256, 256, 0, stream>>>(cw, WtH, WtL);

    for (int l = 0; l < NL; ++l) {
        if (l == 0)
            k_gemm<true><<<(NN + 255) / 256, 256, 0, stream>>>(
                x, WtH, WtL, level2, gam, bet, h1);
        else
            k_gemm<false><<<(NN + 255) / 256, 256, 0, stream>>>(
                h2, WtH + (size_t)l * HH * HH, WtL + (size_t)l * HH * HH,
                level2, gam + (size_t)(l - 1) * HH, bet + (size_t)(l - 1) * HH, h1);
        k_gather<<<NGB, 256, 0, stream>>>(h1, offsets, degi, csr, dinv, h2, partial);
        k_sred1<<<SR1B, 256, 0, stream>>>(partial, mid);
        k_sred2<<<L2B, 256, 0, stream>>>(mid, level2);
    }
    // layer-5 scsh, then materialize x5 (fp16) for the edge head
    k_prep<<<1, 128, 0, stream>>>(level2, gam + (size_t)(NL - 1) * HH,
                                  bet + (size_t)(NL - 1) * HH, scsh);
    k_bnapply<<<(NN * 64 + 255) / 256, 256, 0, stream>>>(h2, scsh, xh);
    k_final<<<(NE * 16 + 255) / 256, 256, 0, stream>>>(xh, ei, fcw, fcb, out);
}